// Round 1
// baseline (1551.846 us; speedup 1.0000x reference)
//
#include <hip/hip_runtime.h>
#include <cstddef>
#include <cstdint>

#define B_ 8
#define C_ 96
#define D_ 192
#define N_ 16
#define R_ 6
#define K_ 4
#define H_ 64
#define W_ 64
#define L_ 4096
#define EPSV 1e-5f

// ---- static scratch (avoids reliance on ws_size); zero-init at load, fully
// overwritten before each read within a launch ----
__device__ __attribute__((aligned(16))) float d_xcpre[(size_t)B_*L_*D_];  // (B,L,D) in_proj half 0
__device__ __attribute__((aligned(16))) float d_z[(size_t)B_*L_*D_];      // (B,L,D) in_proj half 1 (gate)
__device__ __attribute__((aligned(16))) float d_xc[(size_t)B_*L_*D_];     // (B,L,D) conv+SiLU output
__device__ __attribute__((aligned(16))) float d_dt[(size_t)B_*K_*D_*L_];  // (B,K,D,L)
__device__ __attribute__((aligned(16))) float d_Bsv[(size_t)B_*K_*N_*L_]; // (B,K,N,L)
__device__ __attribute__((aligned(16))) float d_Csv[(size_t)B_*K_*N_*L_]; // (B,K,N,L)
__device__ __attribute__((aligned(16))) float d_yb[(size_t)4*B_*D_*L_];   // [k][b][d][l] merged-orientation
__device__ __attribute__((aligned(16))) float d_cwt[9*D_];                // conv w transposed [ky*3+kx][d]
__device__ __attribute__((aligned(16))) float d_w2t[D_*C_];               // out_proj w transposed [d][c]

// ---------------- prep: tiny weight transposes ----------------
__global__ void k0_prep(const float* __restrict__ cw, const float* __restrict__ w2){
  for (int i = threadIdx.x; i < 9*D_; i += 256){
    int d = i / 9, j = i % 9;
    d_cwt[j*D_ + d] = cw[d*9 + j];
  }
  for (int i = threadIdx.x; i < D_*C_; i += 256){
    int dd = i / C_, c = i % C_;
    d_w2t[dd*C_ + c] = w2[c*D_ + dd];
  }
}

// ---------------- k1: BN + in_proj ----------------
// grid (512, 2): x = b*64 + ptile, y = e-half. block 64. thread-per-pixel.
__global__ __launch_bounds__(64,2) void k1_inproj(const float* __restrict__ x,
    const float* __restrict__ bg, const float* __restrict__ bb,
    const float* __restrict__ bm, const float* __restrict__ bv,
    const float* __restrict__ w){
  const int b = blockIdx.x >> 6;
  const int p = ((blockIdx.x & 63) << 6) + threadIdx.x;
  const int half = blockIdx.y;
  float u[C_];
  const float* xb = x + (size_t)b*C_*L_ + p;
#pragma unroll
  for (int c = 0; c < C_; ++c){
    float s = bg[c] * rsqrtf(bv[c] + EPSV);
    float t = bb[c] - bm[c]*s;
    u[c] = fmaf(xb[(size_t)c*L_], s, t);
  }
  const float* wr = w + (size_t)half*D_*C_;
  float* ob = (half ? d_z : d_xcpre) + ((size_t)b*L_ + p)*D_;
  for (int e0 = 0; e0 < D_; e0 += 4){
    float a0=0.f, a1=0.f, a2=0.f, a3=0.f;
#pragma unroll
    for (int c = 0; c < C_; ++c){
      float uc = u[c];
      a0 = fmaf(wr[(e0+0)*C_+c], uc, a0);
      a1 = fmaf(wr[(e0+1)*C_+c], uc, a1);
      a2 = fmaf(wr[(e0+2)*C_+c], uc, a2);
      a3 = fmaf(wr[(e0+3)*C_+c], uc, a3);
    }
    float4 r; r.x=a0; r.y=a1; r.z=a2; r.w=a3;
    *(float4*)(ob + e0) = r;
  }
}

// ---------------- k2: depthwise 3x3 conv + bias + SiLU ----------------
// grid B*H = 512, block 256. channels-last float4.
__global__ __launch_bounds__(256,2) void k2_conv(const float* __restrict__ cb){
  const int b = blockIdx.x >> 6, h = blockIdx.x & 63;
  for (int j = 0; j < 12; ++j){
    const int unit = threadIdx.x + (j << 8);      // 0..3071
    const int d4 = unit % 48, w = unit / 48;
    const int d = d4 << 2;
    float ax=0.f, ay=0.f, az=0.f, aw=0.f;
#pragma unroll
    for (int ky = 0; ky < 3; ++ky){
      const int hh = h + ky - 1;
      if ((unsigned)hh >= (unsigned)H_) continue;  // block-uniform branch
#pragma unroll
      for (int kx = 0; kx < 3; ++kx){
        const int ww = w + kx - 1;
        const bool ok = (unsigned)ww < (unsigned)W_;
        const int wc = ok ? ww : w;
        const float4 v  = *(const float4*)(d_xcpre + ((size_t)b*L_ + hh*W_ + wc)*D_ + d);
        const float4 wt = *(const float4*)(d_cwt + (ky*3+kx)*D_ + d);
        if (ok){
          ax = fmaf(v.x, wt.x, ax); ay = fmaf(v.y, wt.y, ay);
          az = fmaf(v.z, wt.z, az); aw = fmaf(v.w, wt.w, aw);
        }
      }
    }
    const float4 bias = *(const float4*)(cb + d);
    float v0 = ax + bias.x, v1 = ay + bias.y, v2 = az + bias.z, v3 = aw + bias.w;
    float4 o;
    o.x = v0 / (1.f + __expf(-v0));
    o.y = v1 / (1.f + __expf(-v1));
    o.z = v2 / (1.f + __expf(-v2));
    o.w = v3 / (1.f + __expf(-v3));
    *(float4*)(d_xc + ((size_t)b*L_ + h*W_ + w)*D_ + d) = o;
  }
}

// seq index t -> spatial p for direction k
__device__ __forceinline__ int posk(int k, int t){
  if (k == 0) return t;
  if (k == 1) return ((t & 63) << 6) | (t >> 6);
  if (k == 2) return (L_-1) - t;
  int s = (L_-1) - t; return ((s & 63) << 6) | (s >> 6);
}

// ---------------- k3: x_proj + dt (softplus) ----------------
// grid (64, K, B), block 64 (1 wave). thread-per-seq-position.
__global__ __launch_bounds__(64,2) void k3_xproj(const float* __restrict__ xpw,
    const float* __restrict__ dtw, const float* __restrict__ dtb){
  const int lc = blockIdx.x, k = blockIdx.y, b = blockIdx.z;
  const int l = (lc << 6) + threadIdx.x;
  const int p = posk(k, l);
  float u[D_];
  const float4* ur = (const float4*)(d_xc + ((size_t)b*L_ + p)*D_);
#pragma unroll
  for (int q = 0; q < 48; ++q){
    float4 v = ur[q];
    u[4*q+0] = v.x; u[4*q+1] = v.y; u[4*q+2] = v.z; u[4*q+3] = v.w;
  }
  __shared__ float xdbl[64][41];   // pad 41 (odd stride -> conflict-free)
  const float* wk = xpw + (size_t)k*38*D_;
  for (int c = 0; c < 38; ++c){
    float acc = 0.f;
#pragma unroll
    for (int dd = 0; dd < D_; ++dd) acc = fmaf(wk[c*D_+dd], u[dd], acc);
    xdbl[threadIdx.x][c] = acc;
  }
  __syncthreads();
  float xr[R_];
#pragma unroll
  for (int r = 0; r < R_; ++r) xr[r] = xdbl[threadIdx.x][r];
  const int bk = b*K_ + k;
#pragma unroll
  for (int n = 0; n < N_; ++n){
    d_Bsv[((size_t)bk*N_ + n)*L_ + l] = xdbl[threadIdx.x][R_ + n];
    d_Csv[((size_t)bk*N_ + n)*L_ + l] = xdbl[threadIdx.x][R_ + N_ + n];
  }
  const float* wd = dtw + (size_t)k*D_*R_;
  const float* db = dtb + (size_t)k*D_;
  for (int d = 0; d < D_; ++d){
    float a = db[d];
#pragma unroll
    for (int r = 0; r < R_; ++r) a = fmaf(wd[d*R_+r], xr[r], a);
    float sp = (a > 20.f) ? a : log1pf(__expf(a));
    d_dt[((size_t)bk*D_ + d)*L_ + l] = sp;
  }
}

// 16-lane (DPP row) sum: after 4 rotate-adds every lane holds the row total
__device__ __forceinline__ float rowsum16(float v){
  v += __int_as_float(__builtin_amdgcn_update_dpp(0, __float_as_int(v), 0x128, 0xF, 0xF, true)); // ror 8
  v += __int_as_float(__builtin_amdgcn_update_dpp(0, __float_as_int(v), 0x124, 0xF, 0xF, true)); // ror 4
  v += __int_as_float(__builtin_amdgcn_update_dpp(0, __float_as_int(v), 0x122, 0xF, 0xF, true)); // ror 2
  v += __int_as_float(__builtin_amdgcn_update_dpp(0, __float_as_int(v), 0x121, 0xF, 0xF, true)); // ror 1
  return v;
}

// ---------------- k4: selective scan ----------------
// grid (24, K, B) -> 768 blocks (3/CU even), block 128 = 8 d x 16 n.
// 64-step LDS chunks, register-prefetch double buffer, odd-ish padded rows.
#define PADR 68
__global__ __launch_bounds__(128,2) void k4_scan(const float* __restrict__ alog,
    const float* __restrict__ dsk){
  __shared__ float sDT[8][PADR], sDU[8][PADR], sU[8][PADR], sY[8][PADR];
  __shared__ float sB[16][PADR], sC[16][PADR];
  const int dc = blockIdx.x, k = blockIdx.y, b = blockIdx.z;
  const int d0 = dc << 3;
  const int tid = threadIdx.x;
  const int n = tid & 15, dl = tid >> 4;
  const int d = d0 + dl;
  const int bk = b*K_ + k;
  const float Ah  = -__expf(alog[(k*D_ + d)*N_ + n]) * 1.4426950408889634f; // A*log2(e)
  const float Dsv = dsk[k*D_ + d];
  float h = 0.f;
  // staging roles
  const int sr = tid >> 4;            // 8 rows
  const int scc = (tid & 15) << 2;    // 16 x float4 columns
  const float* dtg = d_dt  + ((size_t)bk*D_ + d0 + sr)*L_;
  const float* Bg  = d_Bsv + ((size_t)bk*N_ + sr)*L_;
  const float* Cg  = d_Csv + ((size_t)bk*N_ + sr)*L_;
  const float* ug  = d_xc  + (size_t)b*L_*D_ + d0 + sr;
  float* yb = d_yb + ((size_t)k*B_ + b)*D_*L_ + (size_t)(d0 + sr)*L_;

  float4 rdt, rb0, rb1, rc0, rc1; float ru0, ru1, ru2, ru3;
  auto stage_load = [&](int t0){
    rdt = *(const float4*)(dtg + t0 + scc);
    rb0 = *(const float4*)(Bg + t0 + scc);
    rb1 = *(const float4*)(Bg + (size_t)8*L_ + t0 + scc);
    rc0 = *(const float4*)(Cg + t0 + scc);
    rc1 = *(const float4*)(Cg + (size_t)8*L_ + t0 + scc);
    ru0 = ug[(size_t)posk(k, t0+scc+0)*D_];
    ru1 = ug[(size_t)posk(k, t0+scc+1)*D_];
    ru2 = ug[(size_t)posk(k, t0+scc+2)*D_];
    ru3 = ug[(size_t)posk(k, t0+scc+3)*D_];
  };
  stage_load(0);
  for (int ic = 0; ic < 64; ++ic){
    const int t0 = ic << 6;
    __syncthreads();
    *(float4*)&sDT[sr][scc] = rdt;
    { float4 uu; uu.x=ru0; uu.y=ru1; uu.z=ru2; uu.w=ru3; *(float4*)&sU[sr][scc] = uu; }
    { float4 du; du.x=rdt.x*ru0; du.y=rdt.y*ru1; du.z=rdt.z*ru2; du.w=rdt.w*ru3;
      *(float4*)&sDU[sr][scc] = du; }
    *(float4*)&sB[sr  ][scc] = rb0;
    *(float4*)&sB[sr+8][scc] = rb1;
    *(float4*)&sC[sr  ][scc] = rc0;
    *(float4*)&sC[sr+8][scc] = rc1;
    __syncthreads();
    if (ic < 63) stage_load(t0 + 64);
    for (int tt = 0; tt < 64; tt += 4){
      float4 vdt4 = *(const float4*)&sDT[dl][tt];
      float4 vdu4 = *(const float4*)&sDU[dl][tt];
      float4 vb4  = *(const float4*)&sB[n][tt];
      float4 vc4  = *(const float4*)&sC[n][tt];
      float4 vu4  = *(const float4*)&sU[dl][tt];
      const float* vdt = (const float*)&vdt4;
      const float* vdu = (const float*)&vdu4;
      const float* vb  = (const float*)&vb4;
      const float* vc  = (const float*)&vc4;
      const float* vu  = (const float*)&vu4;
      float yv[4];
#pragma unroll
      for (int j = 0; j < 4; ++j){
        float dA = exp2f(vdt[j] * Ah);
        h = fmaf(dA, h, vdu[j] * vb[j]);
        float s = rowsum16(h * vc[j]);
        yv[j] = fmaf(Dsv, vu[j], s);
      }
      if (n == 0){
        float4 o; o.x=yv[0]; o.y=yv[1]; o.z=yv[2]; o.w=yv[3];
        *(float4*)&sY[dl][tt] = o;
      }
    }
    __syncthreads();
    float4 vy = *(const float4*)&sY[sr][scc];
    if (k < 2){
      *(float4*)(yb + t0 + scc) = vy;                // t-order (== p / wh order)
    } else {
      float4 ry; ry.x=vy.w; ry.y=vy.z; ry.z=vy.y; ry.w=vy.x;
      *(float4*)(yb + (L_ - 4) - t0 - scc) = ry;     // store flipped
    }
  }
}

// ---------------- k5: merge + LN + gate + out_proj + residual ----------------
// grid B*16 (16x16 spatial tiles), block 256, thread-per-pixel, g[192] in regs.
__global__ __launch_bounds__(256,1) void k5_final(const float* __restrict__ x,
    const float* __restrict__ lnw, const float* __restrict__ lnb,
    float* __restrict__ out){
  const int b = blockIdx.x >> 4, tile = blockIdx.x & 15;
  const int h = ((tile >> 2) << 4) + (threadIdx.x >> 4);
  const int w = ((tile & 3) << 4) + (threadIdx.x & 15);
  const int p = (h << 6) + w;
  const int m = (w << 6) + h;
  const float* y0 = d_yb + ((size_t)0*B_ + b)*D_*L_;
  const float* y1 = d_yb + ((size_t)1*B_ + b)*D_*L_;
  const float* y2 = d_yb + ((size_t)2*B_ + b)*D_*L_;
  const float* y3 = d_yb + ((size_t)3*B_ + b)*D_*L_;
  float gv[D_];
  float sum = 0.f, ssq = 0.f;
#pragma unroll
  for (int d = 0; d < D_; ++d){
    float v = (y0[(size_t)d*L_ + p] + y2[(size_t)d*L_ + p])
            + (y1[(size_t)d*L_ + m] + y3[(size_t)d*L_ + m]);
    gv[d] = v; sum += v; ssq = fmaf(v, v, ssq);
  }
  const float mu = sum * (1.f/(float)D_);
  const float var = fmaf(ssq, 1.f/(float)D_, -mu*mu);
  const float rstd = rsqrtf(var + EPSV);
  const float4* zp = (const float4*)(d_z + ((size_t)b*L_ + p)*D_);
#pragma unroll
  for (int q = 0; q < 48; ++q){
    float4 zz = zp[q];
    float s0 = zz.x / (1.f + __expf(-zz.x));
    float s1 = zz.y / (1.f + __expf(-zz.y));
    float s2 = zz.z / (1.f + __expf(-zz.z));
    float s3 = zz.w / (1.f + __expf(-zz.w));
    gv[4*q+0] = (fmaf((gv[4*q+0]-mu)*rstd, lnw[4*q+0], lnb[4*q+0])) * s0;
    gv[4*q+1] = (fmaf((gv[4*q+1]-mu)*rstd, lnw[4*q+1], lnb[4*q+1])) * s1;
    gv[4*q+2] = (fmaf((gv[4*q+2]-mu)*rstd, lnw[4*q+2], lnb[4*q+2])) * s2;
    gv[4*q+3] = (fmaf((gv[4*q+3]-mu)*rstd, lnw[4*q+3], lnb[4*q+3])) * s3;
  }
  for (int cg = 0; cg < 8; ++cg){
    float acc[12];
#pragma unroll
    for (int i = 0; i < 12; ++i) acc[i] = 0.f;
#pragma unroll
    for (int d = 0; d < D_; ++d){
      const float gd = gv[d];
      const float* wrow = d_w2t + d*C_ + cg*12;
#pragma unroll
      for (int i = 0; i < 12; ++i) acc[i] = fmaf(wrow[i], gd, acc[i]);
    }
#pragma unroll
    for (int i = 0; i < 12; ++i){
      const int c = cg*12 + i;
      const size_t o = ((size_t)b*C_ + c)*L_ + p;
      out[o] = x[o] + acc[i];
    }
  }
}

extern "C" void kernel_launch(void* const* d_in, const int* in_sizes, int n_in,
                              void* d_out, int out_size, void* d_ws, size_t ws_size,
                              hipStream_t stream){
  (void)in_sizes; (void)n_in; (void)d_ws; (void)ws_size; (void)out_size;
  const float* x    = (const float*)d_in[0];
  const float* bng  = (const float*)d_in[1];
  const float* bnb  = (const float*)d_in[2];
  const float* bnm  = (const float*)d_in[3];
  const float* bnv  = (const float*)d_in[4];
  const float* ipw  = (const float*)d_in[5];
  const float* cw   = (const float*)d_in[6];
  const float* cb   = (const float*)d_in[7];
  const float* xpw  = (const float*)d_in[8];
  const float* dtw  = (const float*)d_in[9];
  const float* dtb  = (const float*)d_in[10];
  const float* alog = (const float*)d_in[11];
  const float* dsk  = (const float*)d_in[12];
  const float* lnw  = (const float*)d_in[13];
  const float* lnb  = (const float*)d_in[14];
  const float* opw  = (const float*)d_in[15];
  float* out = (float*)d_out;

  hipLaunchKernelGGL(k0_prep,   dim3(1),        dim3(256), 0, stream, cw, opw);
  hipLaunchKernelGGL(k1_inproj, dim3(512, 2),   dim3(64),  0, stream, x, bng, bnb, bnm, bnv, ipw);
  hipLaunchKernelGGL(k2_conv,   dim3(512),      dim3(256), 0, stream, cb);
  hipLaunchKernelGGL(k3_xproj,  dim3(64, 4, 8), dim3(64),  0, stream, xpw, dtw, dtb);
  hipLaunchKernelGGL(k4_scan,   dim3(24, 4, 8), dim3(128), 0, stream, alog, dsk);
  hipLaunchKernelGGL(k5_final,  dim3(128),      dim3(256), 0, stream, x, lnw, lnb, out);
}

// Round 3
// 1052.512 us; speedup vs baseline: 1.4744x; 1.4744x over previous
//
#include <hip/hip_runtime.h>
#include <cstddef>
#include <cstdint>

#define B_ 8
#define C_ 96
#define D_ 192
#define N_ 16
#define R_ 6
#define K_ 4
#define H_ 64
#define W_ 64
#define L_ 4096
#define EPSV 1e-5f
#define LOG2E 1.4426950408889634f

// ---- static scratch; every element written before read within one launch ----
__device__ __attribute__((aligned(16))) float d_xpre[(size_t)B_*D_*L_];  // in_proj half0 (B,D,L)
__device__ __attribute__((aligned(16))) float d_z[(size_t)B_*D_*L_];     // gate (B,D,L)
__device__ __attribute__((aligned(16))) float d_xch[(size_t)B_*D_*L_];   // conv out, row-major spatial
__device__ __attribute__((aligned(16))) float d_xcw[(size_t)B_*D_*L_];   // conv out, col-major spatial
__device__ __attribute__((aligned(16))) float d_dt[(size_t)B_*K_*D_*L_];
__device__ __attribute__((aligned(16))) float d_Bsv[(size_t)B_*K_*N_*L_];
__device__ __attribute__((aligned(16))) float d_Csv[(size_t)B_*K_*N_*L_];
__device__ __attribute__((aligned(16))) float d_yb[(size_t)K_*B_*D_*L_];
__device__ __attribute__((aligned(16))) float d_yT[(size_t)B_*D_*L_];    // transpose of y1+y3
__device__ __attribute__((aligned(16))) float d_g[(size_t)B_*D_*L_];     // gated LN output (B,D,L)
__device__ __attribute__((aligned(16))) float d_xpwT[K_*D_*40];          // [k][dd][c<38, pad 40]
__device__ __attribute__((aligned(16))) float d_w2T[D_*C_];              // [d][c]

// ---------------- k0: weight transposes ----------------
__global__ void k0_prep(const float* __restrict__ xpw, const float* __restrict__ w2){
  for (int i = threadIdx.x; i < K_*D_*38; i += 256){
    int k = i / (D_*38); int rem = i % (D_*38); int dd = rem / 38; int c = rem % 38;
    d_xpwT[(k*D_ + dd)*40 + c] = xpw[((size_t)k*38 + c)*D_ + dd];
  }
  for (int i = threadIdx.x; i < D_*C_; i += 256){
    int d = i / C_, c = i % C_;
    d_w2T[d*C_ + c] = w2[c*D_ + d];
  }
}

// ---------------- k1: BN + in_proj, channel-first outputs ----------------
// grid (512, 2, 2): x = b*64+ptile, y = half (xc|z), z = e-range split. block 64.
__global__ __launch_bounds__(64,2) void k1_inproj(const float* __restrict__ x,
    const float* __restrict__ bg, const float* __restrict__ bb,
    const float* __restrict__ bm, const float* __restrict__ bv,
    const float* __restrict__ w){
  const int b = blockIdx.x >> 6;
  const int p = ((blockIdx.x & 63) << 6) + threadIdx.x;
  const int half = blockIdx.y;
  const int e_lo = blockIdx.z * (D_/2), e_hi = e_lo + (D_/2);
  float u[C_];
  const float* xb = x + (size_t)b*C_*L_ + p;
#pragma unroll
  for (int c = 0; c < C_; ++c){
    float s = bg[c] * rsqrtf(bv[c] + EPSV);
    float t = bb[c] - bm[c]*s;
    u[c] = fmaf(xb[(size_t)c*L_], s, t);
  }
  const float* wr = w + (size_t)half*D_*C_;
  float* ob = (half ? d_z : d_xpre) + (size_t)b*D_*L_ + p;
  for (int e0 = e_lo; e0 < e_hi; e0 += 4){
    float a0=0.f, a1=0.f, a2=0.f, a3=0.f;
#pragma unroll
    for (int c = 0; c < C_; ++c){
      float uc = u[c];
      a0 = fmaf(wr[(e0+0)*C_+c], uc, a0);
      a1 = fmaf(wr[(e0+1)*C_+c], uc, a1);
      a2 = fmaf(wr[(e0+2)*C_+c], uc, a2);
      a3 = fmaf(wr[(e0+3)*C_+c], uc, a3);
    }
    ob[(size_t)(e0+0)*L_] = a0;
    ob[(size_t)(e0+1)*L_] = a1;
    ob[(size_t)(e0+2)*L_] = a2;
    ob[(size_t)(e0+3)*L_] = a3;
  }
}

// ---------------- k2: depthwise 3x3 + SiLU, dual-layout output ----------------
// grid (D, B), block 256. One (b,d) 64x64 plane per block, LDS halo tile.
__global__ __launch_bounds__(256,2) void k2_conv(const float* __restrict__ cw,
                                                 const float* __restrict__ cb){
  __shared__ float lds[66*68];
  const int d = blockIdx.x, b = blockIdx.y;
  const float* src = d_xpre + ((size_t)b*D_ + d)*L_;
  for (int i = threadIdx.x; i < 66*68; i += 256) lds[i] = 0.f;
  __syncthreads();
#pragma unroll
  for (int it = 0; it < 16; ++it){
    int idx = threadIdx.x + (it<<8);
    int h = idx >> 6, w = idx & 63;
    lds[(h+1)*68 + (w+1)] = src[idx];
  }
  float wt[9];
#pragma unroll
  for (int j = 0; j < 9; ++j) wt[j] = cw[d*9 + j];
  const float bias = cb[d];
  __syncthreads();
  float ov[16];
#pragma unroll
  for (int it = 0; it < 16; ++it){
    int idx = threadIdx.x + (it<<8);
    int h = idx >> 6, w = idx & 63;
    const float* c0 = &lds[h*68 + w];
    float a = c0[0]*wt[0] + c0[1]*wt[1] + c0[2]*wt[2]
            + c0[68]*wt[3] + c0[69]*wt[4] + c0[70]*wt[5]
            + c0[136]*wt[6] + c0[137]*wt[7] + c0[138]*wt[8];
    a += bias;
    ov[it] = a / (1.f + __expf(-a));
  }
  __syncthreads();                       // done with input tile
#pragma unroll
  for (int it = 0; it < 16; ++it){       // out-tile [64][65] for transpose
    int idx = threadIdx.x + (it<<8);
    int h = idx >> 6, w = idx & 63;
    lds[h*65 + w] = ov[it];
  }
  float* dsth = d_xch + ((size_t)b*D_ + d)*L_;
  float* dstw = d_xcw + ((size_t)b*D_ + d)*L_;
#pragma unroll
  for (int it = 0; it < 16; ++it){
    int idx = threadIdx.x + (it<<8);
    dsth[idx] = ov[it];
  }
  __syncthreads();
#pragma unroll
  for (int it = 0; it < 16; ++it){
    int m = threadIdx.x + (it<<8);       // col-major index
    int h = m & 63, w = m >> 6;
    dstw[m] = lds[h*65 + w];
  }
}

// ---------------- k3: x_proj + dt, wave-structured ----------------
// grid (16, K, B), block 256 = 4 waves x 64 seq positions. 38 accs/lane.
__global__ __launch_bounds__(256,2) void k3_xproj(const float* __restrict__ dtw,
                                                  const float* __restrict__ dtb){
  const int wv = threadIdx.x >> 6, lane = threadIdx.x & 63;
  const int k = blockIdx.y, b = blockIdx.z;
  const int l = (blockIdx.x << 8) + (wv << 6) + lane;
  const int bk = b*K_ + k;
  const float* src = ((k & 1) ? d_xcw : d_xch) + (size_t)b*D_*L_;
  const int idx = (k < 2) ? l : (L_ - 1 - l);
  float acc[38];
#pragma unroll
  for (int c = 0; c < 38; ++c) acc[c] = 0.f;
  const float* wrow = d_xpwT + (size_t)k*D_*40;
#pragma unroll 4
  for (int dd = 0; dd < D_; ++dd){
    const float uv = src[(size_t)dd*L_ + idx];
    const float* wc = wrow + dd*40;
#pragma unroll
    for (int c = 0; c < 38; ++c) acc[c] = fmaf(wc[c], uv, acc[c]);
  }
#pragma unroll
  for (int n = 0; n < N_; ++n){
    d_Bsv[((size_t)bk*N_ + n)*L_ + l] = acc[R_ + n];
    d_Csv[((size_t)bk*N_ + n)*L_ + l] = acc[R_ + N_ + n];
  }
  const float* wd = dtw + (size_t)k*D_*R_;
  const float* db = dtb + (size_t)k*D_;
  for (int d = 0; d < D_; ++d){
    float a = db[d];
#pragma unroll
    for (int r = 0; r < R_; ++r) a = fmaf(wd[d*R_+r], acc[r], a);
    float sp = (a > 20.f) ? a : __logf(1.f + __expf(a));
    d_dt[((size_t)bk*D_ + d)*L_ + l] = sp;
  }
}

// 16-lane DPP row sum
__device__ __forceinline__ float rowsum16(float v){
  v += __int_as_float(__builtin_amdgcn_update_dpp(0, __float_as_int(v), 0x128, 0xF, 0xF, true));
  v += __int_as_float(__builtin_amdgcn_update_dpp(0, __float_as_int(v), 0x124, 0xF, 0xF, true));
  v += __int_as_float(__builtin_amdgcn_update_dpp(0, __float_as_int(v), 0x122, 0xF, 0xF, true));
  v += __int_as_float(__builtin_amdgcn_update_dpp(0, __float_as_int(v), 0x121, 0xF, 0xF, true));
  return v;
}

// ---------------- k4: selective scan ----------------
#define PADR 68
__global__ __launch_bounds__(128,2) void k4_scan(const float* __restrict__ alog,
                                                 const float* __restrict__ dsk){
  __shared__ float sDT[8][PADR], sDU[8][PADR], sU[8][PADR], sY[8][PADR];
  __shared__ float sB[16][PADR], sC[16][PADR];
  const int dc = blockIdx.x, k = blockIdx.y, b = blockIdx.z;
  const int d0 = dc << 3;
  const int tid = threadIdx.x;
  const int n = tid & 15, dl = tid >> 4;
  const int d = d0 + dl;
  const int bk = b*K_ + k;
  const float Ah  = -__expf(alog[(k*D_ + d)*N_ + n]) * LOG2E;
  const float Dsv = dsk[k*D_ + d];
  float h = 0.f;
  const int sr = tid >> 4;
  const int scc = (tid & 15) << 2;
  const float* dtg = d_dt  + ((size_t)bk*D_ + d0 + sr)*L_;
  const float* Bg  = d_Bsv + ((size_t)bk*N_ + sr)*L_;
  const float* Cg  = d_Csv + ((size_t)bk*N_ + sr)*L_;
  const float* ug  = ((k & 1) ? d_xcw : d_xch) + ((size_t)b*D_ + d0 + sr)*L_;
  float* yb = d_yb + (((size_t)k*B_ + b)*D_ + d0 + sr)*L_;

  float4 rdt, rb0, rb1, rc0, rc1, ru;
  auto stage_load = [&](int t0){
    rdt = *(const float4*)(dtg + t0 + scc);
    rb0 = *(const float4*)(Bg + t0 + scc);
    rb1 = *(const float4*)(Bg + (size_t)8*L_ + t0 + scc);
    rc0 = *(const float4*)(Cg + t0 + scc);
    rc1 = *(const float4*)(Cg + (size_t)8*L_ + t0 + scc);
    if (k < 2){
      ru = *(const float4*)(ug + t0 + scc);
    } else {
      float4 raw = *(const float4*)(ug + (L_ - 4) - t0 - scc);
      ru.x = raw.w; ru.y = raw.z; ru.z = raw.y; ru.w = raw.x;
    }
  };
  stage_load(0);
  for (int ic = 0; ic < 64; ++ic){
    const int t0 = ic << 6;
    __syncthreads();
    *(float4*)&sDT[sr][scc] = rdt;
    *(float4*)&sU[sr][scc]  = ru;
    { float4 du; du.x=rdt.x*ru.x; du.y=rdt.y*ru.y; du.z=rdt.z*ru.z; du.w=rdt.w*ru.w;
      *(float4*)&sDU[sr][scc] = du; }
    *(float4*)&sB[sr  ][scc] = rb0;
    *(float4*)&sB[sr+8][scc] = rb1;
    *(float4*)&sC[sr  ][scc] = rc0;
    *(float4*)&sC[sr+8][scc] = rc1;
    __syncthreads();
    if (ic < 63) stage_load(t0 + 64);
    for (int tt = 0; tt < 64; tt += 4){
      float4 vdt4 = *(const float4*)&sDT[dl][tt];
      float4 vdu4 = *(const float4*)&sDU[dl][tt];
      float4 vb4  = *(const float4*)&sB[n][tt];
      float4 vc4  = *(const float4*)&sC[n][tt];
      float4 vu4  = *(const float4*)&sU[dl][tt];
      const float* vdt = (const float*)&vdt4;
      const float* vdu = (const float*)&vdu4;
      const float* vb  = (const float*)&vb4;
      const float* vc  = (const float*)&vc4;
      const float* vu  = (const float*)&vu4;
      float yv[4];
#pragma unroll
      for (int j = 0; j < 4; ++j){
        float dA = exp2f(vdt[j] * Ah);
        h = fmaf(dA, h, vdu[j] * vb[j]);
        float s = rowsum16(h * vc[j]);
        yv[j] = fmaf(Dsv, vu[j], s);
      }
      if (n == 0){
        float4 o; o.x=yv[0]; o.y=yv[1]; o.z=yv[2]; o.w=yv[3];
        *(float4*)&sY[dl][tt] = o;
      }
    }
    __syncthreads();
    float4 vy = *(const float4*)&sY[sr][scc];
    if (k < 2){
      *(float4*)(yb + t0 + scc) = vy;
    } else {
      float4 ry; ry.x=vy.w; ry.y=vy.z; ry.z=vy.y; ry.w=vy.x;
      *(float4*)(yb + (L_ - 4) - t0 - scc) = ry;
    }
  }
}

// ---------------- k4b: batched 64x64 transpose of (y1+y3) ----------------
// grid (D, B), block 256.
__global__ __launch_bounds__(256,2) void k4b_transpose(){
  __shared__ float lds[64*65];
  const int d = blockIdx.x, b = blockIdx.y;
  const float* y1 = d_yb + (((size_t)1*B_ + b)*D_ + d)*L_;
  const float* y3 = d_yb + (((size_t)3*B_ + b)*D_ + d)*L_;
  float* o = d_yT + ((size_t)b*D_ + d)*L_;
#pragma unroll
  for (int it = 0; it < 16; ++it){
    int m = threadIdx.x + (it<<8);
    int h = m & 63, w = m >> 6;
    lds[h*65 + w] = y1[m] + y3[m];
  }
  __syncthreads();
#pragma unroll
  for (int it = 0; it < 16; ++it){
    int p = threadIdx.x + (it<<8);
    int h = p >> 6, w = p & 63;
    o[p] = lds[h*65 + w];
  }
}

// ---------------- k5a: merge + LN + gate ----------------
// grid 512, block 256 = 4 waves (one d-group each) x 64 pixels.
__global__ __launch_bounds__(256,2) void k5a_merge(const float* __restrict__ lnw,
                                                   const float* __restrict__ lnb){
  __shared__ float ssum[64*5], ssq2[64*5];
  const int b = blockIdx.x >> 6;
  const int px = threadIdx.x & 63;
  const int p = ((blockIdx.x & 63) << 6) + px;
  const int g = threadIdx.x >> 6;
  const size_t plane = (size_t)b*D_*L_;
  const float* y0 = d_yb + ((size_t)0*B_ + b)*D_*L_;
  const float* y2 = d_yb + ((size_t)2*B_ + b)*D_*L_;
  float sum = 0.f, ssq = 0.f;
#pragma unroll
  for (int i = 0; i < 48; ++i){
    int dd = g*48 + i;
    float v = y0[(size_t)dd*L_ + p] + y2[(size_t)dd*L_ + p] + d_yT[plane + (size_t)dd*L_ + p];
    sum += v; ssq = fmaf(v, v, ssq);
  }
  ssum[px*5+g] = sum; ssq2[px*5+g] = ssq;
  __syncthreads();
  float ts = ssum[px*5+0]+ssum[px*5+1]+ssum[px*5+2]+ssum[px*5+3];
  float tq = ssq2[px*5+0]+ssq2[px*5+1]+ssq2[px*5+2]+ssq2[px*5+3];
  const float mu = ts * (1.f/(float)D_);
  const float var = tq*(1.f/(float)D_) - mu*mu;
  const float rstd = rsqrtf(var + EPSV);
#pragma unroll
  for (int i = 0; i < 48; ++i){
    int dd = g*48 + i;
    float v = y0[(size_t)dd*L_ + p] + y2[(size_t)dd*L_ + p] + d_yT[plane + (size_t)dd*L_ + p];
    float zz = d_z[plane + (size_t)dd*L_ + p];
    float sz = zz / (1.f + __expf(-zz));
    d_g[plane + (size_t)dd*L_ + p] = fmaf((v-mu)*rstd, lnw[dd], lnb[dd]) * sz;
  }
}

// ---------------- k5b: out_proj + residual ----------------
// grid 256, block 256 = 4 waves: 2 p-chunks x 2 c-halves. 48 accs/lane.
__global__ __launch_bounds__(256,2) void k5b_outproj(const float* __restrict__ x,
                                                     float* __restrict__ out){
  const int b = blockIdx.x >> 5;
  const int wv = threadIdx.x >> 6, lane = threadIdx.x & 63;
  const int pch = wv & 1, ch = wv >> 1;
  const int p = ((blockIdx.x & 31) << 7) + (pch << 6) + lane;
  const int c0 = ch * 48;
  float acc[48];
#pragma unroll
  for (int i = 0; i < 48; ++i) acc[i] = 0.f;
  const float* gb = d_g + (size_t)b*D_*L_ + p;
#pragma unroll 4
  for (int d = 0; d < D_; ++d){
    float gv = gb[(size_t)d*L_];
    const float* wr = d_w2T + d*C_ + c0;
#pragma unroll
    for (int i = 0; i < 48; ++i) acc[i] = fmaf(wr[i], gv, acc[i]);
  }
  const float* xb = x + (size_t)b*C_*L_ + p;
  float* ob = out + (size_t)b*C_*L_ + p;
#pragma unroll
  for (int i = 0; i < 48; ++i){
    int c = c0 + i;
    ob[(size_t)c*L_] = xb[(size_t)c*L_] + acc[i];
  }
}

extern "C" void kernel_launch(void* const* d_in, const int* in_sizes, int n_in,
                              void* d_out, int out_size, void* d_ws, size_t ws_size,
                              hipStream_t stream){
  (void)in_sizes; (void)n_in; (void)d_ws; (void)ws_size; (void)out_size;
  const float* x    = (const float*)d_in[0];
  const float* bng  = (const float*)d_in[1];
  const float* bnb  = (const float*)d_in[2];
  const float* bnm  = (const float*)d_in[3];
  const float* bnv  = (const float*)d_in[4];
  const float* ipw  = (const float*)d_in[5];
  const float* cw   = (const float*)d_in[6];
  const float* cb   = (const float*)d_in[7];
  const float* xpw  = (const float*)d_in[8];
  const float* dtw  = (const float*)d_in[9];
  const float* dtb  = (const float*)d_in[10];
  const float* alog = (const float*)d_in[11];
  const float* dsk  = (const float*)d_in[12];
  const float* lnw  = (const float*)d_in[13];
  const float* lnb  = (const float*)d_in[14];
  const float* opw  = (const float*)d_in[15];
  float* out = (float*)d_out;

  hipLaunchKernelGGL(k0_prep,      dim3(1),          dim3(256), 0, stream, xpw, opw);
  hipLaunchKernelGGL(k1_inproj,    dim3(512, 2, 2),  dim3(64),  0, stream, x, bng, bnb, bnm, bnv, ipw);
  hipLaunchKernelGGL(k2_conv,      dim3(D_, B_),     dim3(256), 0, stream, cw, cb);
  hipLaunchKernelGGL(k3_xproj,     dim3(16, 4, 8),   dim3(256), 0, stream, dtw, dtb);
  hipLaunchKernelGGL(k4_scan,      dim3(24, 4, 8),   dim3(128), 0, stream, alog, dsk);
  hipLaunchKernelGGL(k4b_transpose,dim3(D_, B_),     dim3(256), 0, stream);
  hipLaunchKernelGGL(k5a_merge,    dim3(512),        dim3(256), 0, stream, lnw, lnb);
  hipLaunchKernelGGL(k5b_outproj,  dim3(256),        dim3(256), 0, stream, x, out);
}

// Round 6
// 892.664 us; speedup vs baseline: 1.7384x; 1.1791x over previous
//
#include <hip/hip_runtime.h>
#include <cstddef>
#include <cstdint>

#define B_ 8
#define C_ 96
#define D_ 192
#define N_ 16
#define R_ 6
#define K_ 4
#define H_ 64
#define W_ 64
#define L_ 4096
#define EPSV 1e-5f
#define LOG2E 1.4426950408889634f

#define SSEG 8
#define TSEG (L_/SSEG)     /* 512 */
#define CH   (TSEG/64)     /* 8 chunks per segment */

// ---- static scratch; every element written before read within one launch ----
__device__ __attribute__((aligned(16))) float d_xpre[(size_t)B_*D_*L_];  // in_proj half0 (B,D,L)
__device__ __attribute__((aligned(16))) float d_z[(size_t)B_*D_*L_];     // gate (B,D,L)
__device__ __attribute__((aligned(16))) float d_xch[(size_t)B_*D_*L_];   // conv out, row-major spatial
__device__ __attribute__((aligned(16))) float d_xcw[(size_t)B_*D_*L_];   // conv out, col-major spatial
__device__ __attribute__((aligned(16))) float d_dt[(size_t)B_*K_*D_*L_];
__device__ __attribute__((aligned(16))) float d_Bsv[(size_t)B_*K_*N_*L_];
__device__ __attribute__((aligned(16))) float d_Csv[(size_t)B_*K_*N_*L_];
__device__ __attribute__((aligned(16))) float d_yb[(size_t)K_*B_*D_*L_];
__device__ __attribute__((aligned(16))) float d_yT[(size_t)B_*D_*L_];    // transpose of y1+y3
__device__ __attribute__((aligned(16))) float d_g[(size_t)B_*D_*L_];     // gated LN output (B,D,L)
__device__ __attribute__((aligned(16))) float d_xpwT[K_*D_*40];          // [k][dd][c<38, pad 40]
__device__ __attribute__((aligned(16))) float d_w2T[D_*C_];              // [d][c]
// segmented-scan state: [bk][s][d][n]
__device__ __attribute__((aligned(16))) float d_hend[(size_t)B_*K_*SSEG*D_*N_];
__device__ __attribute__((aligned(16))) float d_P[(size_t)B_*K_*SSEG*D_*N_];
__device__ __attribute__((aligned(16))) float d_h0[(size_t)B_*K_*SSEG*D_*N_];

// ---------------- k0: weight transposes ----------------
__global__ void k0_prep(const float* __restrict__ xpw, const float* __restrict__ w2){
  for (int i = threadIdx.x; i < K_*D_*38; i += 256){
    int k = i / (D_*38); int rem = i % (D_*38); int dd = rem / 38; int c = rem % 38;
    d_xpwT[(k*D_ + dd)*40 + c] = xpw[((size_t)k*38 + c)*D_ + dd];
  }
  for (int i = threadIdx.x; i < D_*C_; i += 256){
    int d = i / C_, c = i % C_;
    d_w2T[d*C_ + c] = w2[c*D_ + d];
  }
}

// ---------------- k1: BN + in_proj, channel-first outputs ----------------
// grid (512, 2, 4): x = b*64+ptile, y = half (xc|z), z = e-range quarter. block 64.
__global__ __launch_bounds__(64,2) void k1_inproj(const float* __restrict__ x,
    const float* __restrict__ bg, const float* __restrict__ bb,
    const float* __restrict__ bm, const float* __restrict__ bv,
    const float* __restrict__ w){
  const int b = blockIdx.x >> 6;
  const int p = ((blockIdx.x & 63) << 6) + threadIdx.x;
  const int half = blockIdx.y;
  const int e_lo = blockIdx.z * (D_/4), e_hi = e_lo + (D_/4);
  float u[C_];
  const float* xb = x + (size_t)b*C_*L_ + p;
#pragma unroll
  for (int c = 0; c < C_; ++c){
    float s = bg[c] * rsqrtf(bv[c] + EPSV);
    float t = bb[c] - bm[c]*s;
    u[c] = fmaf(xb[(size_t)c*L_], s, t);
  }
  const float* wr = w + (size_t)half*D_*C_;
  float* ob = (half ? d_z : d_xpre) + (size_t)b*D_*L_ + p;
  for (int e0 = e_lo; e0 < e_hi; e0 += 4){
    float a0=0.f, a1=0.f, a2=0.f, a3=0.f;
#pragma unroll
    for (int c = 0; c < C_; ++c){
      float uc = u[c];
      a0 = fmaf(wr[(e0+0)*C_+c], uc, a0);
      a1 = fmaf(wr[(e0+1)*C_+c], uc, a1);
      a2 = fmaf(wr[(e0+2)*C_+c], uc, a2);
      a3 = fmaf(wr[(e0+3)*C_+c], uc, a3);
    }
    ob[(size_t)(e0+0)*L_] = a0;
    ob[(size_t)(e0+1)*L_] = a1;
    ob[(size_t)(e0+2)*L_] = a2;
    ob[(size_t)(e0+3)*L_] = a3;
  }
}

// ---------------- k2: depthwise 3x3 + SiLU, dual-layout output ----------------
__global__ __launch_bounds__(256,2) void k2_conv(const float* __restrict__ cw,
                                                 const float* __restrict__ cb){
  __shared__ float lds[66*68];
  const int d = blockIdx.x, b = blockIdx.y;
  const float* src = d_xpre + ((size_t)b*D_ + d)*L_;
  for (int i = threadIdx.x; i < 66*68; i += 256) lds[i] = 0.f;
  __syncthreads();
#pragma unroll
  for (int it = 0; it < 16; ++it){
    int idx = threadIdx.x + (it<<8);
    int h = idx >> 6, w = idx & 63;
    lds[(h+1)*68 + (w+1)] = src[idx];
  }
  float wt[9];
#pragma unroll
  for (int j = 0; j < 9; ++j) wt[j] = cw[d*9 + j];
  const float bias = cb[d];
  __syncthreads();
  float ov[16];
#pragma unroll
  for (int it = 0; it < 16; ++it){
    int idx = threadIdx.x + (it<<8);
    int h = idx >> 6, w = idx & 63;
    const float* c0 = &lds[h*68 + w];
    float a = c0[0]*wt[0] + c0[1]*wt[1] + c0[2]*wt[2]
            + c0[68]*wt[3] + c0[69]*wt[4] + c0[70]*wt[5]
            + c0[136]*wt[6] + c0[137]*wt[7] + c0[138]*wt[8];
    a += bias;
    ov[it] = a / (1.f + __expf(-a));
  }
  __syncthreads();
#pragma unroll
  for (int it = 0; it < 16; ++it){
    int idx = threadIdx.x + (it<<8);
    int h = idx >> 6, w = idx & 63;
    lds[h*65 + w] = ov[it];
  }
  float* dsth = d_xch + ((size_t)b*D_ + d)*L_;
  float* dstw = d_xcw + ((size_t)b*D_ + d)*L_;
#pragma unroll
  for (int it = 0; it < 16; ++it){
    int idx = threadIdx.x + (it<<8);
    dsth[idx] = ov[it];
  }
  __syncthreads();
#pragma unroll
  for (int it = 0; it < 16; ++it){
    int m = threadIdx.x + (it<<8);
    int h = m & 63, w = m >> 6;
    dstw[m] = lds[h*65 + w];
  }
}

// ---------------- k3: x_proj + dt, wave-structured ----------------
__global__ __launch_bounds__(256,2) void k3_xproj(const float* __restrict__ dtw,
                                                  const float* __restrict__ dtb){
  const int wv = threadIdx.x >> 6, lane = threadIdx.x & 63;
  const int k = blockIdx.y, b = blockIdx.z;
  const int l = (blockIdx.x << 8) + (wv << 6) + lane;
  const int bk = b*K_ + k;
  const float* src = ((k & 1) ? d_xcw : d_xch) + (size_t)b*D_*L_;
  const int idx = (k < 2) ? l : (L_ - 1 - l);
  float acc[38];
#pragma unroll
  for (int c = 0; c < 38; ++c) acc[c] = 0.f;
  const float* wrow = d_xpwT + (size_t)k*D_*40;
#pragma unroll 4
  for (int dd = 0; dd < D_; ++dd){
    const float uv = src[(size_t)dd*L_ + idx];
    const float* wc = wrow + dd*40;
#pragma unroll
    for (int c = 0; c < 38; ++c) acc[c] = fmaf(wc[c], uv, acc[c]);
  }
#pragma unroll
  for (int n = 0; n < N_; ++n){
    d_Bsv[((size_t)bk*N_ + n)*L_ + l] = acc[R_ + n];
    d_Csv[((size_t)bk*N_ + n)*L_ + l] = acc[R_ + N_ + n];
  }
  const float* wd = dtw + (size_t)k*D_*R_;
  const float* db = dtb + (size_t)k*D_;
  for (int d = 0; d < D_; ++d){
    float a = db[d];
#pragma unroll
    for (int r = 0; r < R_; ++r) a = fmaf(wd[d*R_+r], acc[r], a);
    float sp = (a > 20.f) ? a : __logf(1.f + __expf(a));
    d_dt[((size_t)bk*D_ + d)*L_ + l] = sp;
  }
}

// 16-lane DPP row sum
__device__ __forceinline__ float rowsum16(float v){
  v += __int_as_float(__builtin_amdgcn_update_dpp(0, __float_as_int(v), 0x128, 0xF, 0xF, true));
  v += __int_as_float(__builtin_amdgcn_update_dpp(0, __float_as_int(v), 0x124, 0xF, 0xF, true));
  v += __int_as_float(__builtin_amdgcn_update_dpp(0, __float_as_int(v), 0x122, 0xF, 0xF, true));
  v += __int_as_float(__builtin_amdgcn_update_dpp(0, __float_as_int(v), 0x121, 0xF, 0xF, true));
  return v;
}

// ---------------- k4a: per-segment local scan -> h_end, P ----------------
// grid (24*SSEG, K, B), block 128 = 8 d x 16 n.
#define PADR 68
__global__ __launch_bounds__(128,2) void k4a_local(const float* __restrict__ alog){
  __shared__ float sDT[8][PADR], sDU[8][PADR], sB[16][PADR];
  const int dc = blockIdx.x % 24, s = blockIdx.x / 24;
  const int k = blockIdx.y, b = blockIdx.z;
  const int d0 = dc << 3;
  const int tid = threadIdx.x;
  const int n = tid & 15, dl = tid >> 4;
  const int d = d0 + dl;
  const int bk = b*K_ + k;
  const float Ah = -__expf(alog[(k*D_ + d)*N_ + n]) * LOG2E;
  float h = 0.f, sdt = 0.f;
  const int sr = tid >> 4;
  const int scc = (tid & 15) << 2;
  const float* dtg = d_dt  + ((size_t)bk*D_ + d0 + sr)*L_;
  const float* Bg  = d_Bsv + ((size_t)bk*N_ + sr)*L_;
  const float* ug  = ((k & 1) ? d_xcw : d_xch) + ((size_t)b*D_ + d0 + sr)*L_;
  float4 rdt, rb0, rb1, ru;
  auto stage_load = [&](int t0){
    rdt = *(const float4*)(dtg + t0 + scc);
    rb0 = *(const float4*)(Bg + t0 + scc);
    rb1 = *(const float4*)(Bg + (size_t)8*L_ + t0 + scc);
    if (k < 2){
      ru = *(const float4*)(ug + t0 + scc);
    } else {
      float4 raw = *(const float4*)(ug + (L_ - 4) - t0 - scc);
      ru.x = raw.w; ru.y = raw.z; ru.z = raw.y; ru.w = raw.x;
    }
  };
  const int tbase = s*TSEG;
  stage_load(tbase);
  for (int ic = 0; ic < CH; ++ic){
    const int t0 = tbase + (ic << 6);
    __syncthreads();
    *(float4*)&sDT[sr][scc] = rdt;
    { float4 du; du.x=rdt.x*ru.x; du.y=rdt.y*ru.y; du.z=rdt.z*ru.z; du.w=rdt.w*ru.w;
      *(float4*)&sDU[sr][scc] = du; }
    *(float4*)&sB[sr  ][scc] = rb0;
    *(float4*)&sB[sr+8][scc] = rb1;
    __syncthreads();
    if (ic < CH-1) stage_load(t0 + 64);
    for (int tt = 0; tt < 64; tt += 4){
      float4 vdt4 = *(const float4*)&sDT[dl][tt];
      float4 vdu4 = *(const float4*)&sDU[dl][tt];
      float4 vb4  = *(const float4*)&sB[n][tt];
      const float* vdt = (const float*)&vdt4;
      const float* vdu = (const float*)&vdu4;
      const float* vb  = (const float*)&vb4;
#pragma unroll
      for (int j = 0; j < 4; ++j){
        sdt += vdt[j];
        float dA = exp2f(vdt[j] * Ah);
        h = fmaf(dA, h, vdu[j] * vb[j]);
      }
    }
  }
  const size_t oidx = (((size_t)bk*SSEG + s)*D_ + d)*N_ + n;
  d_hend[oidx] = h;
  d_P[oidx] = exp2f(Ah * sdt);   // exact product of per-step decays
}

// ---------------- k4c: inter-segment combine (tiny) ----------------
// grid 384, block 256: one thread per (bk,d,n).
__global__ __launch_bounds__(256,4) void k4c_combine(){
  const int gid = blockIdx.x*256 + threadIdx.x;       // 0..98303
  const int bk = gid / (D_*N_);
  const int rem = gid % (D_*N_);
  const size_t base = (size_t)bk*SSEG*D_*N_ + rem;
  float h = 0.f;
#pragma unroll
  for (int s = 0; s < SSEG; ++s){
    const size_t idx = base + (size_t)s*D_*N_;
    d_h0[idx] = h;
    h = fmaf(d_P[idx], h, d_hend[idx]);
  }
}

// ---------------- k4: selective scan (per segment, from h0) ----------------
// grid (24*SSEG, K, B), block 128 = 8 d x 16 n.
__global__ __launch_bounds__(128,2) void k4_scan(const float* __restrict__ alog,
                                                 const float* __restrict__ dsk){
  __shared__ float sDT[8][PADR], sDU[8][PADR], sU[8][PADR], sY[8][PADR];
  __shared__ float sB[16][PADR], sC[16][PADR];
  const int dc = blockIdx.x % 24, s = blockIdx.x / 24;
  const int k = blockIdx.y, b = blockIdx.z;
  const int d0 = dc << 3;
  const int tid = threadIdx.x;
  const int n = tid & 15, dl = tid >> 4;
  const int d = d0 + dl;
  const int bk = b*K_ + k;
  const float Ah  = -__expf(alog[(k*D_ + d)*N_ + n]) * LOG2E;
  const float Dsv = dsk[k*D_ + d];
  float h = d_h0[(((size_t)bk*SSEG + s)*D_ + d)*N_ + n];
  const int sr = tid >> 4;
  const int scc = (tid & 15) << 2;
  const float* dtg = d_dt  + ((size_t)bk*D_ + d0 + sr)*L_;
  const float* Bg  = d_Bsv + ((size_t)bk*N_ + sr)*L_;
  const float* Cg  = d_Csv + ((size_t)bk*N_ + sr)*L_;
  const float* ug  = ((k & 1) ? d_xcw : d_xch) + ((size_t)b*D_ + d0 + sr)*L_;
  float* yb = d_yb + (((size_t)k*B_ + b)*D_ + d0 + sr)*L_;

  float4 rdt, rb0, rb1, rc0, rc1, ru;
  auto stage_load = [&](int t0){
    rdt = *(const float4*)(dtg + t0 + scc);
    rb0 = *(const float4*)(Bg + t0 + scc);
    rb1 = *(const float4*)(Bg + (size_t)8*L_ + t0 + scc);
    rc0 = *(const float4*)(Cg + t0 + scc);
    rc1 = *(const float4*)(Cg + (size_t)8*L_ + t0 + scc);
    if (k < 2){
      ru = *(const float4*)(ug + t0 + scc);
    } else {
      float4 raw = *(const float4*)(ug + (L_ - 4) - t0 - scc);
      ru.x = raw.w; ru.y = raw.z; ru.z = raw.y; ru.w = raw.x;
    }
  };
  const int tbase = s*TSEG;
  stage_load(tbase);
  for (int ic = 0; ic < CH; ++ic){
    const int t0 = tbase + (ic << 6);
    __syncthreads();
    *(float4*)&sDT[sr][scc] = rdt;
    *(float4*)&sU[sr][scc]  = ru;
    { float4 du; du.x=rdt.x*ru.x; du.y=rdt.y*ru.y; du.z=rdt.z*ru.z; du.w=rdt.w*ru.w;
      *(float4*)&sDU[sr][scc] = du; }
    *(float4*)&sB[sr  ][scc] = rb0;
    *(float4*)&sB[sr+8][scc] = rb1;
    *(float4*)&sC[sr  ][scc] = rc0;
    *(float4*)&sC[sr+8][scc] = rc1;
    __syncthreads();
    if (ic < CH-1) stage_load(t0 + 64);
    for (int tt = 0; tt < 64; tt += 4){
      float4 vdt4 = *(const float4*)&sDT[dl][tt];
      float4 vdu4 = *(const float4*)&sDU[dl][tt];
      float4 vb4  = *(const float4*)&sB[n][tt];
      float4 vc4  = *(const float4*)&sC[n][tt];
      float4 vu4  = *(const float4*)&sU[dl][tt];
      const float* vdt = (const float*)&vdt4;
      const float* vdu = (const float*)&vdu4;
      const float* vb  = (const float*)&vb4;
      const float* vc  = (const float*)&vc4;
      const float* vu  = (const float*)&vu4;
      float yv[4];
#pragma unroll
      for (int j = 0; j < 4; ++j){
        float dA = exp2f(vdt[j] * Ah);
        h = fmaf(dA, h, vdu[j] * vb[j]);
        float ss = rowsum16(h * vc[j]);
        yv[j] = fmaf(Dsv, vu[j], ss);
      }
      if (n == 0){
        float4 o; o.x=yv[0]; o.y=yv[1]; o.z=yv[2]; o.w=yv[3];
        *(float4*)&sY[dl][tt] = o;
      }
    }
    __syncthreads();
    float4 vy = *(const float4*)&sY[sr][scc];
    if (k < 2){
      *(float4*)(yb + t0 + scc) = vy;
    } else {
      float4 ry; ry.x=vy.w; ry.y=vy.z; ry.z=vy.y; ry.w=vy.x;
      *(float4*)(yb + (L_ - 4) - t0 - scc) = ry;
    }
  }
}

// ---------------- k4b: batched 64x64 transpose of (y1+y3) ----------------
__global__ __launch_bounds__(256,2) void k4b_transpose(){
  __shared__ float lds[64*65];
  const int d = blockIdx.x, b = blockIdx.y;
  const float* y1 = d_yb + (((size_t)1*B_ + b)*D_ + d)*L_;
  const float* y3 = d_yb + (((size_t)3*B_ + b)*D_ + d)*L_;
  float* o = d_yT + ((size_t)b*D_ + d)*L_;
#pragma unroll
  for (int it = 0; it < 16; ++it){
    int m = threadIdx.x + (it<<8);
    int h = m & 63, w = m >> 6;
    lds[h*65 + w] = y1[m] + y3[m];
  }
  __syncthreads();
#pragma unroll
  for (int it = 0; it < 16; ++it){
    int p = threadIdx.x + (it<<8);
    int h = p >> 6, w = p & 63;
    o[p] = lds[h*65 + w];
  }
}

// ---------------- k5a: merge + LN + gate ----------------
__global__ __launch_bounds__(256,2) void k5a_merge(const float* __restrict__ lnw,
                                                   const float* __restrict__ lnb){
  __shared__ float ssum[64*5], ssq2[64*5];
  const int b = blockIdx.x >> 6;
  const int px = threadIdx.x & 63;
  const int p = ((blockIdx.x & 63) << 6) + px;
  const int g = threadIdx.x >> 6;
  const size_t plane = (size_t)b*D_*L_;
  const float* y0 = d_yb + ((size_t)0*B_ + b)*D_*L_;
  const float* y2 = d_yb + ((size_t)2*B_ + b)*D_*L_;
  float sum = 0.f, ssq = 0.f;
#pragma unroll
  for (int i = 0; i < 48; ++i){
    int dd = g*48 + i;
    float v = y0[(size_t)dd*L_ + p] + y2[(size_t)dd*L_ + p] + d_yT[plane + (size_t)dd*L_ + p];
    sum += v; ssq = fmaf(v, v, ssq);
  }
  ssum[px*5+g] = sum; ssq2[px*5+g] = ssq;
  __syncthreads();
  float ts = ssum[px*5+0]+ssum[px*5+1]+ssum[px*5+2]+ssum[px*5+3];
  float tq = ssq2[px*5+0]+ssq2[px*5+1]+ssq2[px*5+2]+ssq2[px*5+3];
  const float mu = ts * (1.f/(float)D_);
  const float var = tq*(1.f/(float)D_) - mu*mu;
  const float rstd = rsqrtf(var + EPSV);
#pragma unroll
  for (int i = 0; i < 48; ++i){
    int dd = g*48 + i;
    float v = y0[(size_t)dd*L_ + p] + y2[(size_t)dd*L_ + p] + d_yT[plane + (size_t)dd*L_ + p];
    float zz = d_z[plane + (size_t)dd*L_ + p];
    float sz = zz / (1.f + __expf(-zz));
    d_g[plane + (size_t)dd*L_ + p] = fmaf((v-mu)*rstd, lnw[dd], lnb[dd]) * sz;
  }
}

// ---------------- k5b: out_proj + residual ----------------
__global__ __launch_bounds__(256,2) void k5b_outproj(const float* __restrict__ x,
                                                     float* __restrict__ out){
  const int b = blockIdx.x >> 5;
  const int wv = threadIdx.x >> 6, lane = threadIdx.x & 63;
  const int pch = wv & 1, ch = wv >> 1;
  const int p = ((blockIdx.x & 31) << 7) + (pch << 6) + lane;
  const int c0 = ch * 48;
  float acc[48];
#pragma unroll
  for (int i = 0; i < 48; ++i) acc[i] = 0.f;
  const float* gb = d_g + (size_t)b*D_*L_ + p;
#pragma unroll 4
  for (int d = 0; d < D_; ++d){
    float gv = gb[(size_t)d*L_];
    const float* wr = d_w2T + d*C_ + c0;
#pragma unroll
    for (int i = 0; i < 48; ++i) acc[i] = fmaf(wr[i], gv, acc[i]);
  }
  const float* xb = x + (size_t)b*C_*L_ + p;
  float* ob = out + (size_t)b*C_*L_ + p;
#pragma unroll
  for (int i = 0; i < 48; ++i){
    int c = c0 + i;
    ob[(size_t)c*L_] = xb[(size_t)c*L_] + acc[i];
  }
}

extern "C" void kernel_launch(void* const* d_in, const int* in_sizes, int n_in,
                              void* d_out, int out_size, void* d_ws, size_t ws_size,
                              hipStream_t stream){
  (void)in_sizes; (void)n_in; (void)d_ws; (void)ws_size; (void)out_size;
  const float* x    = (const float*)d_in[0];
  const float* bng  = (const float*)d_in[1];
  const float* bnb  = (const float*)d_in[2];
  const float* bnm  = (const float*)d_in[3];
  const float* bnv  = (const float*)d_in[4];
  const float* ipw  = (const float*)d_in[5];
  const float* cw   = (const float*)d_in[6];
  const float* cb   = (const float*)d_in[7];
  const float* xpw  = (const float*)d_in[8];
  const float* dtw  = (const float*)d_in[9];
  const float* dtb  = (const float*)d_in[10];
  const float* alog = (const float*)d_in[11];
  const float* dsk  = (const float*)d_in[12];
  const float* lnw  = (const float*)d_in[13];
  const float* lnb  = (const float*)d_in[14];
  const float* opw  = (const float*)d_in[15];
  float* out = (float*)d_out;

  hipLaunchKernelGGL(k0_prep,      dim3(1),             dim3(256), 0, stream, xpw, opw);
  hipLaunchKernelGGL(k1_inproj,    dim3(512, 2, 4),     dim3(64),  0, stream, x, bng, bnb, bnm, bnv, ipw);
  hipLaunchKernelGGL(k2_conv,      dim3(D_, B_),        dim3(256), 0, stream, cw, cb);
  hipLaunchKernelGGL(k3_xproj,     dim3(16, 4, 8),      dim3(256), 0, stream, dtw, dtb);
  hipLaunchKernelGGL(k4a_local,    dim3(24*SSEG, 4, 8), dim3(128), 0, stream, alog);
  hipLaunchKernelGGL(k4c_combine,  dim3(384),           dim3(256), 0, stream);
  hipLaunchKernelGGL(k4_scan,      dim3(24*SSEG, 4, 8), dim3(128), 0, stream, alog, dsk);
  hipLaunchKernelGGL(k4b_transpose,dim3(D_, B_),        dim3(256), 0, stream);
  hipLaunchKernelGGL(k5a_merge,    dim3(512),           dim3(256), 0, stream, lnw, lnb);
  hipLaunchKernelGGL(k5b_outproj,  dim3(256),           dim3(256), 0, stream, x, out);
}

// Round 9
// 741.303 us; speedup vs baseline: 2.0934x; 1.2042x over previous
//
#include <hip/hip_runtime.h>
#include <cstddef>
#include <cstdint>

#define B_ 8
#define C_ 96
#define D_ 192
#define N_ 16
#define R_ 6
#define K_ 4
#define H_ 64
#define W_ 64
#define L_ 4096
#define EPSV 1e-5f
#define LOG2E 1.4426950408889634f

#define SSEG 64            /* segments for the two-pass scan */
#define TSEG (L_/SSEG)     /* 64 timesteps per segment */

// ---- static scratch; every element written before read within one launch ----
__device__ __attribute__((aligned(16))) float d_xpre[(size_t)B_*D_*L_];  // in_proj half0 (B,D,L)
__device__ __attribute__((aligned(16))) float d_z[(size_t)B_*D_*L_];     // gate (B,D,L)
__device__ __attribute__((aligned(16))) float d_xch[(size_t)B_*D_*L_];   // conv out, row-major spatial
__device__ __attribute__((aligned(16))) float d_xcw[(size_t)B_*D_*L_];   // conv out, col-major spatial
__device__ __attribute__((aligned(16))) float d_dtT[(size_t)B_*K_*L_*D_]; // dt, [bk][t][d]
__device__ __attribute__((aligned(16))) float d_duT[(size_t)B_*K_*L_*D_]; // dt*u, [bk][t][d]
__device__ __attribute__((aligned(16))) float d_BsT[(size_t)B_*K_*L_*N_]; // [bk][t][n]
__device__ __attribute__((aligned(16))) float d_CsT[(size_t)B_*K_*L_*N_]; // [bk][t][n]
__device__ __attribute__((aligned(16))) float d_yb[(size_t)K_*B_*L_*D_];  // [k][b][row][d], flips pre-unflipped
__device__ __attribute__((aligned(16))) float d_g[(size_t)B_*D_*L_];     // gated LN output (B,D,L)
__device__ __attribute__((aligned(16))) float d_xpwT[K_*D_*40];          // [k][dd][c<38, pad 40]
__device__ __attribute__((aligned(16))) float d_w2T[D_*C_];              // [d][c]
__device__ __attribute__((aligned(16))) float d_sumDs[D_];               // sum_k Ds[k][d]
// segmented-scan state: [bk][s][d][n]
__device__ __attribute__((aligned(16))) float d_hend[(size_t)B_*K_*SSEG*D_*N_];
__device__ __attribute__((aligned(16))) float d_P[(size_t)B_*K_*SSEG*D_*N_];
__device__ __attribute__((aligned(16))) float d_h0[(size_t)B_*K_*SSEG*D_*N_];

__device__ __forceinline__ float ex2(float x){
#if __has_builtin(__builtin_amdgcn_exp2f)
  return __builtin_amdgcn_exp2f(x);
#else
  float r; asm volatile("v_exp_f32 %0, %1" : "=v"(r) : "v"(x)); return r;
#endif
}
__device__ __forceinline__ float frcp(float x){
#if __has_builtin(__builtin_amdgcn_rcpf)
  return __builtin_amdgcn_rcpf(x);
#else
  return 1.f / x;
#endif
}
// order prior ds_writes vs later ds_reads within one wave (wave-synchronous blocks)
__device__ __forceinline__ void wave_lds_fence(){
  asm volatile("s_waitcnt lgkmcnt(0)" ::: "memory");
}

// ---------------- k0: weight transposes + sumDs ----------------
__global__ void k0_prep(const float* __restrict__ xpw, const float* __restrict__ w2,
                        const float* __restrict__ dsk){
  for (int i = threadIdx.x; i < K_*D_*38; i += 256){
    int k = i / (D_*38); int rem = i % (D_*38); int dd = rem / 38; int c = rem % 38;
    d_xpwT[(k*D_ + dd)*40 + c] = xpw[((size_t)k*38 + c)*D_ + dd];
  }
  for (int i = threadIdx.x; i < D_*C_; i += 256){
    int d = i / C_, c = i % C_;
    d_w2T[d*C_ + c] = w2[c*D_ + d];
  }
  for (int i = threadIdx.x; i < D_; i += 256){
    d_sumDs[i] = dsk[i] + dsk[D_+i] + dsk[2*D_+i] + dsk[3*D_+i];
  }
}

// ---------------- k1: BN + in_proj, channel-first outputs (unchanged) ----------------
__global__ __launch_bounds__(64,2) void k1_inproj(const float* __restrict__ x,
    const float* __restrict__ bg, const float* __restrict__ bb,
    const float* __restrict__ bm, const float* __restrict__ bv,
    const float* __restrict__ w){
  const int b = blockIdx.x >> 6;
  const int p = ((blockIdx.x & 63) << 6) + threadIdx.x;
  const int half = blockIdx.y;
  const int e_lo = blockIdx.z * (D_/4), e_hi = e_lo + (D_/4);
  float u[C_];
  const float* xb = x + (size_t)b*C_*L_ + p;
#pragma unroll
  for (int c = 0; c < C_; ++c){
    float s = bg[c] * rsqrtf(bv[c] + EPSV);
    float t = bb[c] - bm[c]*s;
    u[c] = fmaf(xb[(size_t)c*L_], s, t);
  }
  const float* wr = w + (size_t)half*D_*C_;
  float* ob = (half ? d_z : d_xpre) + (size_t)b*D_*L_ + p;
  for (int e0 = e_lo; e0 < e_hi; e0 += 4){
    float a0=0.f, a1=0.f, a2=0.f, a3=0.f;
#pragma unroll
    for (int c = 0; c < C_; ++c){
      float uc = u[c];
      a0 = fmaf(wr[(e0+0)*C_+c], uc, a0);
      a1 = fmaf(wr[(e0+1)*C_+c], uc, a1);
      a2 = fmaf(wr[(e0+2)*C_+c], uc, a2);
      a3 = fmaf(wr[(e0+3)*C_+c], uc, a3);
    }
    ob[(size_t)(e0+0)*L_] = a0;
    ob[(size_t)(e0+1)*L_] = a1;
    ob[(size_t)(e0+2)*L_] = a2;
    ob[(size_t)(e0+3)*L_] = a3;
  }
}

// ---------------- k2: depthwise 3x3 + SiLU, dual-layout output (unchanged) ----------------
__global__ __launch_bounds__(256,2) void k2_conv(const float* __restrict__ cw,
                                                 const float* __restrict__ cb){
  __shared__ float lds[66*68];
  const int d = blockIdx.x, b = blockIdx.y;
  const float* src = d_xpre + ((size_t)b*D_ + d)*L_;
  for (int i = threadIdx.x; i < 66*68; i += 256) lds[i] = 0.f;
  __syncthreads();
#pragma unroll
  for (int it = 0; it < 16; ++it){
    int idx = threadIdx.x + (it<<8);
    int h = idx >> 6, w = idx & 63;
    lds[(h+1)*68 + (w+1)] = src[idx];
  }
  float wt[9];
#pragma unroll
  for (int j = 0; j < 9; ++j) wt[j] = cw[d*9 + j];
  const float bias = cb[d];
  __syncthreads();
  float ov[16];
#pragma unroll
  for (int it = 0; it < 16; ++it){
    int idx = threadIdx.x + (it<<8);
    int h = idx >> 6, w = idx & 63;
    const float* c0 = &lds[h*68 + w];
    float a = c0[0]*wt[0] + c0[1]*wt[1] + c0[2]*wt[2]
            + c0[68]*wt[3] + c0[69]*wt[4] + c0[70]*wt[5]
            + c0[136]*wt[6] + c0[137]*wt[7] + c0[138]*wt[8];
    a += bias;
    ov[it] = a / (1.f + __expf(-a));
  }
  __syncthreads();
#pragma unroll
  for (int it = 0; it < 16; ++it){
    int idx = threadIdx.x + (it<<8);
    int h = idx >> 6, w = idx & 63;
    lds[h*65 + w] = ov[it];
  }
  float* dsth = d_xch + ((size_t)b*D_ + d)*L_;
  float* dstw = d_xcw + ((size_t)b*D_ + d)*L_;
#pragma unroll
  for (int it = 0; it < 16; ++it){
    int idx = threadIdx.x + (it<<8);
    dsth[idx] = ov[it];
  }
  __syncthreads();
#pragma unroll
  for (int it = 0; it < 16; ++it){
    int m = threadIdx.x + (it<<8);
    int h = m & 63, w = m >> 6;
    dstw[m] = lds[h*65 + w];
  }
}

// ---------------- k3: x_proj + dt/du, T-layout outputs via per-wave LDS transpose ----------------
// grid (16, K, B), block 256 = 4 waves x 64 seq positions.
__global__ __launch_bounds__(256,2) void k3_xproj(const float* __restrict__ dtw,
                                                  const float* __restrict__ dtb){
  __shared__ float T[4][64][36];           // per-wave tile, 36 = 16B-aligned stride
  const int wv = threadIdx.x >> 6, lane = threadIdx.x & 63;
  const int k = blockIdx.y, b = blockIdx.z;
  const int l0w = (blockIdx.x << 8) + (wv << 6);
  const int l = l0w + lane;
  const int bk = b*K_ + k;
  const float* src = ((k & 1) ? d_xcw : d_xch) + (size_t)b*D_*L_;
  const int idx = (k < 2) ? l : (L_ - 1 - l);
  float acc[38];
#pragma unroll
  for (int c = 0; c < 38; ++c) acc[c] = 0.f;
  const float* wrow = d_xpwT + (size_t)k*D_*40;
#pragma unroll 4
  for (int dd = 0; dd < D_; ++dd){
    const float uv = src[(size_t)dd*L_ + idx];
    const float* wc = wrow + dd*40;
#pragma unroll
    for (int c = 0; c < 38; ++c) acc[c] = fmaf(wc[c], uv, acc[c]);
  }
  float (*Tw)[36] = T[wv];
  // B (acc[6..21]) -> cols 0..15 ; C (acc[22..37]) -> cols 16..31
#pragma unroll
  for (int j = 0; j < 4; ++j){
    float4 vb; vb.x=acc[6+4*j]; vb.y=acc[7+4*j]; vb.z=acc[8+4*j]; vb.w=acc[9+4*j];
    *(float4*)&Tw[lane][4*j] = vb;
    float4 vc; vc.x=acc[22+4*j]; vc.y=acc[23+4*j]; vc.z=acc[24+4*j]; vc.w=acc[25+4*j];
    *(float4*)&Tw[lane][16+4*j] = vc;
  }
  wave_lds_fence();
  {
    const int lsub = lane >> 2, jb = lane & 3;
#pragma unroll
    for (int i = 0; i < 4; ++i){
      const int row = (i<<4) + lsub;
      float4 vb = *(const float4*)&Tw[row][4*jb];
      *(float4*)(d_BsT + ((size_t)bk*L_ + l0w + row)*16 + 4*jb) = vb;
      float4 vc = *(const float4*)&Tw[row][16 + 4*jb];
      *(float4*)(d_CsT + ((size_t)bk*L_ + l0w + row)*16 + 4*jb) = vc;
    }
  }
  wave_lds_fence();
  const float* wd = dtw + (size_t)k*D_*R_;
  const float* db = dtb + (size_t)k*D_;
  const int lr = lane >> 3, jd = lane & 7;
#pragma unroll 1
  for (int c6 = 0; c6 < 6; ++c6){
    const int d0c = c6*32;
    float dtv[32];
#pragma unroll
    for (int q = 0; q < 8; ++q){
      float4 v;
#pragma unroll
      for (int i = 0; i < 4; ++i){
        const int d = d0c + 4*q + i;
        float a = db[d];
#pragma unroll
        for (int r = 0; r < R_; ++r) a = fmaf(wd[d*R_+r], acc[r], a);
        const float sp = (a > 20.f) ? a : __logf(1.f + __expf(a));
        dtv[4*q+i] = sp;
        ((float*)&v)[i] = sp;
      }
      *(float4*)&Tw[lane][4*q] = v;
    }
    wave_lds_fence();
#pragma unroll
    for (int i = 0; i < 8; ++i){
      const int row = (i<<3) + lr;
      float4 v = *(const float4*)&Tw[row][4*jd];
      *(float4*)(d_dtT + ((size_t)bk*L_ + l0w + row)*D_ + d0c + 4*jd) = v;
    }
    wave_lds_fence();
#pragma unroll
    for (int q = 0; q < 8; ++q){
      float4 v;
#pragma unroll
      for (int i = 0; i < 4; ++i){
        const int d = d0c + 4*q + i;
        ((float*)&v)[i] = dtv[4*q+i] * src[(size_t)d*L_ + idx];
      }
      *(float4*)&Tw[lane][4*q] = v;
    }
    wave_lds_fence();
#pragma unroll
    for (int i = 0; i < 8; ++i){
      const int row = (i<<3) + lr;
      float4 v = *(const float4*)&Tw[row][4*jd];
      *(float4*)(d_duT + ((size_t)bk*L_ + l0w + row)*D_ + d0c + 4*jd) = v;
    }
    wave_lds_fence();
  }
}

// ---------------- scan step macros (layout B: lane=d, N=16 in regs) ----------------
#define SCAN_H16(DT,DU,B0,B1,B2,B3) \
  h[0] = fmaf(ex2((DT)*Ah[0]), h[0], (DU)*(B0).x); \
  h[1] = fmaf(ex2((DT)*Ah[1]), h[1], (DU)*(B0).y); \
  h[2] = fmaf(ex2((DT)*Ah[2]), h[2], (DU)*(B0).z); \
  h[3] = fmaf(ex2((DT)*Ah[3]), h[3], (DU)*(B0).w); \
  h[4] = fmaf(ex2((DT)*Ah[4]), h[4], (DU)*(B1).x); \
  h[5] = fmaf(ex2((DT)*Ah[5]), h[5], (DU)*(B1).y); \
  h[6] = fmaf(ex2((DT)*Ah[6]), h[6], (DU)*(B1).z); \
  h[7] = fmaf(ex2((DT)*Ah[7]), h[7], (DU)*(B1).w); \
  h[8] = fmaf(ex2((DT)*Ah[8]), h[8], (DU)*(B2).x); \
  h[9] = fmaf(ex2((DT)*Ah[9]), h[9], (DU)*(B2).y); \
  h[10] = fmaf(ex2((DT)*Ah[10]), h[10], (DU)*(B2).z); \
  h[11] = fmaf(ex2((DT)*Ah[11]), h[11], (DU)*(B2).w); \
  h[12] = fmaf(ex2((DT)*Ah[12]), h[12], (DU)*(B3).x); \
  h[13] = fmaf(ex2((DT)*Ah[13]), h[13], (DU)*(B3).y); \
  h[14] = fmaf(ex2((DT)*Ah[14]), h[14], (DU)*(B3).z); \
  h[15] = fmaf(ex2((DT)*Ah[15]), h[15], (DU)*(B3).w);

#define YDOT16(C0,C1,C2,C3,Y) \
  Y = fmaf(h[0],(C0).x, Y); Y = fmaf(h[1],(C0).y, Y); Y = fmaf(h[2],(C0).z, Y); Y = fmaf(h[3],(C0).w, Y); \
  Y = fmaf(h[4],(C1).x, Y); Y = fmaf(h[5],(C1).y, Y); Y = fmaf(h[6],(C1).z, Y); Y = fmaf(h[7],(C1).w, Y); \
  Y = fmaf(h[8],(C2).x, Y); Y = fmaf(h[9],(C2).y, Y); Y = fmaf(h[10],(C2).z, Y); Y = fmaf(h[11],(C2).w, Y); \
  Y = fmaf(h[12],(C3).x, Y); Y = fmaf(h[13],(C3).y, Y); Y = fmaf(h[14],(C3).z, Y); Y = fmaf(h[15],(C3).w, Y);

#define LD8(TT,UU,CC) { const float* _p = dtp + (size_t)(CC)*8*D_; const float* _q = dup + (size_t)(CC)*8*D_; \
  _Pragma("unroll") for (int _j = 0; _j < 8; ++_j){ TT[_j] = _p[(size_t)_j*D_]; UU[_j] = _q[(size_t)_j*D_]; } }

// ---------------- k4a: pass 1, per-segment h_end & P ----------------
// grid (3, SSEG, BK), block 64 (1 wave, lane = d within d-group).
__global__ __launch_bounds__(64,3) void k4a_local(const float* __restrict__ alog){
  __shared__ float sB[TSEG*16];
  const int dg = blockIdx.x, s = blockIdx.y, bk = blockIdx.z;
  const int b = bk >> 2, k = bk & 3;
  const int lane = threadIdx.x;
  const int d = (dg<<6) + lane;
  float Ah[16];
#pragma unroll
  for (int j = 0; j < 4; ++j){
    float4 a4 = *(const float4*)(alog + (size_t)(k*D_ + d)*16 + 4*j);
    Ah[4*j+0] = -ex2(a4.x*LOG2E)*LOG2E;
    Ah[4*j+1] = -ex2(a4.y*LOG2E)*LOG2E;
    Ah[4*j+2] = -ex2(a4.z*LOG2E)*LOG2E;
    Ah[4*j+3] = -ex2(a4.w*LOG2E)*LOG2E;
  }
  const float* Bb = d_BsT + ((size_t)bk*L_ + (s<<6))*16;
#pragma unroll
  for (int j = 0; j < 4; ++j){
    float4 v = *(const float4*)(Bb + 4*(lane + (j<<6)));
    *(float4*)&sB[4*(lane + (j<<6))] = v;
  }
  wave_lds_fence();
  float h[16];
#pragma unroll
  for (int i = 0; i < 16; ++i) h[i] = 0.f;
  float sdt = 0.f;
  const float* dtp = d_dtT + ((size_t)bk*L_ + (s<<6))*D_ + d;
  const float* dup = d_duT + ((size_t)bk*L_ + (s<<6))*D_ + d;
  float tA[8], uA[8], tB[8], uB[8];
#define ST8A(TT,UU,CC) { _Pragma("unroll") for (int _j = 0; _j < 8; ++_j){ \
    const float _dt = TT[_j], _du = UU[_j]; sdt += _dt; \
    const float* _br = sB + ((((CC)<<3)+_j)<<4); \
    const float4 _b0 = *(const float4*)_br, _b1 = *(const float4*)(_br+4), \
                 _b2 = *(const float4*)(_br+8), _b3 = *(const float4*)(_br+12); \
    SCAN_H16(_dt,_du,_b0,_b1,_b2,_b3); } }
  LD8(tA,uA,0);
#pragma unroll 1
  for (int c = 0; c < 8; c += 2){
    if (c + 1 < 8) LD8(tB,uB,c+1);
    ST8A(tA,uA,c);
    if (c + 2 < 8) LD8(tA,uA,c+2);
    if (c + 1 < 8) ST8A(tB,uB,c+1);
  }
#undef ST8A
  const size_t ob = ((size_t)bk*SSEG + s)*D_*16 + (size_t)d*16;
#pragma unroll
  for (int j = 0; j < 4; ++j){
    float4 v; v.x=h[4*j]; v.y=h[4*j+1]; v.z=h[4*j+2]; v.w=h[4*j+3];
    *(float4*)(d_hend + ob + 4*j) = v;
    float4 p; p.x=ex2(Ah[4*j]*sdt); p.y=ex2(Ah[4*j+1]*sdt);
    p.z=ex2(Ah[4*j+2]*sdt); p.w=ex2(Ah[4*j+3]*sdt);
    *(float4*)(d_P + ob + 4*j) = p;
  }
}

// ---------------- k4c: inter-segment combine ----------------
__global__ __launch_bounds__(256,4) void k4c_combine(){
  const int gid = blockIdx.x*256 + threadIdx.x;       // 0..98303
  const int bk = gid / (D_*16);
  const int rem = gid % (D_*16);
  const size_t base = (size_t)bk*SSEG*D_*16 + rem;
  float h = 0.f;
#pragma unroll 1
  for (int s = 0; s < SSEG; ++s){
    const size_t idx2 = base + (size_t)s*D_*16;
    d_h0[idx2] = h;
    h = fmaf(d_P[idx2], h, d_hend[idx2]);
  }
}

// ---------------- k4: pass 2, full scan from h0, y -> [row][d] ----------------
// grid (3, SSEG, BK), block 64.
__global__ __launch_bounds__(64,3) void k4_scan(const float* __restrict__ alog){
  __shared__ float sB[TSEG*16], sC[TSEG*16];
  const int dg = blockIdx.x, s = blockIdx.y, bk = blockIdx.z;
  const int b = bk >> 2, k = bk & 3;
  const int lane = threadIdx.x;
  const int d = (dg<<6) + lane;
  float Ah[16];
#pragma unroll
  for (int j = 0; j < 4; ++j){
    float4 a4 = *(const float4*)(alog + (size_t)(k*D_ + d)*16 + 4*j);
    Ah[4*j+0] = -ex2(a4.x*LOG2E)*LOG2E;
    Ah[4*j+1] = -ex2(a4.y*LOG2E)*LOG2E;
    Ah[4*j+2] = -ex2(a4.z*LOG2E)*LOG2E;
    Ah[4*j+3] = -ex2(a4.w*LOG2E)*LOG2E;
  }
  const float* Bb = d_BsT + ((size_t)bk*L_ + (s<<6))*16;
  const float* Cb = d_CsT + ((size_t)bk*L_ + (s<<6))*16;
#pragma unroll
  for (int j = 0; j < 4; ++j){
    float4 v = *(const float4*)(Bb + 4*(lane + (j<<6)));
    *(float4*)&sB[4*(lane + (j<<6))] = v;
    float4 w = *(const float4*)(Cb + 4*(lane + (j<<6)));
    *(float4*)&sC[4*(lane + (j<<6))] = w;
  }
  wave_lds_fence();
  float h[16];
  const size_t hb = ((size_t)bk*SSEG + s)*D_*16 + (size_t)d*16;
#pragma unroll
  for (int j = 0; j < 4; ++j){
    float4 v = *(const float4*)(d_h0 + hb + 4*j);
    h[4*j] = v.x; h[4*j+1] = v.y; h[4*j+2] = v.z; h[4*j+3] = v.w;
  }
  const float* dtp = d_dtT + ((size_t)bk*L_ + (s<<6))*D_ + d;
  const float* dup = d_duT + ((size_t)bk*L_ + (s<<6))*D_ + d;
  float* yb = d_yb + (size_t)(k*B_ + b)*L_*D_ + d;
  const int tb0 = s << 6;
  const bool flip = (k >= 2);
  float tA[8], uA[8], tB[8], uB[8];
#define ST8B(TT,UU,CC) { _Pragma("unroll") for (int _j = 0; _j < 8; ++_j){ \
    const float _dt = TT[_j], _du = UU[_j]; \
    const int _t = ((CC)<<3) + _j; \
    const float* _br = sB + (_t<<4); const float* _cr = sC + (_t<<4); \
    const float4 _b0 = *(const float4*)_br, _b1 = *(const float4*)(_br+4), \
                 _b2 = *(const float4*)(_br+8), _b3 = *(const float4*)(_br+12); \
    const float4 _c0 = *(const float4*)_cr, _c1 = *(const float4*)(_cr+4), \
                 _c2 = *(const float4*)(_cr+8), _c3 = *(const float4*)(_cr+12); \
    SCAN_H16(_dt,_du,_b0,_b1,_b2,_b3); \
    float _y = 0.f; YDOT16(_c0,_c1,_c2,_c3,_y); \
    const int _row = flip ? (L_ - 1 - (tb0 + _t)) : (tb0 + _t); \
    yb[(size_t)_row*D_] = _y; } }
  LD8(tA,uA,0);
#pragma unroll 1
  for (int c = 0; c < 8; c += 2){
    if (c + 1 < 8) LD8(tB,uB,c+1);
    ST8B(tA,uA,c);
    if (c + 2 < 8) LD8(tA,uA,c+2);
    if (c + 1 < 8) ST8B(tB,uB,c+1);
  }
#undef ST8B
}

// ---------------- k5a: merge 4 dirs + skip + LN + gate ----------------
// grid 512 (b*64 + h), block 64 (1 wave); thread = w (pixel within row).
__global__ __launch_bounds__(64,2) void k5a_merge(const float* __restrict__ lnw,
                                                  const float* __restrict__ lnb){
  __shared__ float TV[64][196];       // [w][d], stride 196 = 16B-aligned
  const int hh = blockIdx.x & 63, b = blockIdx.x >> 6;
  const int lane = threadIdx.x;
  const int p0 = hh << 6;
  const float* Y0 = d_yb + (size_t)(0*B_ + b)*L_*D_;
  const float* Y1 = d_yb + (size_t)(1*B_ + b)*L_*D_;
  const float* Y2 = d_yb + (size_t)(2*B_ + b)*L_*D_;
  const float* Y3 = d_yb + (size_t)(3*B_ + b)*L_*D_;
  const int j4 = lane << 2;           // col for lanes < 48
#pragma unroll 4
  for (int w = 0; w < 64; ++w){
    if (lane < 48){
      const size_t rp = (size_t)(p0 + w)*D_ + j4;
      const size_t rm = (size_t)((w<<6) + hh)*D_ + j4;
      float4 a = *(const float4*)(Y0 + rp);
      float4 c = *(const float4*)(Y2 + rp);
      float4 e = *(const float4*)(Y1 + rm);
      float4 f = *(const float4*)(Y3 + rm);
      a.x += c.x + e.x + f.x;
      a.y += c.y + e.y + f.y;
      a.z += c.z + e.z + f.z;
      a.w += c.w + e.w + f.w;
      *(float4*)&TV[w][j4] = a;
    }
  }
  wave_lds_fence();
  // phase 2: add skip term, LN statistics (thread = pixel w = lane)
  const float* xr = d_xch + (size_t)b*D_*L_ + p0 + lane;
  float sum = 0.f, sq = 0.f;
#pragma unroll 4
  for (int q = 0; q < 48; ++q){
    float4 tv = *(float4*)&TV[lane][4*q];
    const int dd = 4*q;
    tv.x = fmaf(d_sumDs[dd+0], xr[(size_t)(dd+0)*L_], tv.x);
    tv.y = fmaf(d_sumDs[dd+1], xr[(size_t)(dd+1)*L_], tv.y);
    tv.z = fmaf(d_sumDs[dd+2], xr[(size_t)(dd+2)*L_], tv.z);
    tv.w = fmaf(d_sumDs[dd+3], xr[(size_t)(dd+3)*L_], tv.w);
    *(float4*)&TV[lane][4*q] = tv;
    sum += tv.x + tv.y + tv.z + tv.w;
    sq = fmaf(tv.x,tv.x, fmaf(tv.y,tv.y, fmaf(tv.z,tv.z, fmaf(tv.w,tv.w, sq))));
  }
  const float mu = sum * (1.f/(float)D_);
  const float var = fmaf(sq, 1.f/(float)D_, -mu*mu);
  const float rstd = rsqrtf(var + EPSV);
  // phase 3: normalize + gate
  const float* zr = d_z + (size_t)b*D_*L_ + p0 + lane;
  float* gr = d_g + (size_t)b*D_*L_ + p0 + lane;
#pragma unroll 4
  for (int q = 0; q < 48; ++q){
    float4 tv = *(const float4*)&TV[lane][4*q];
    const int dd = 4*q;
#pragma unroll
    for (int i = 0; i < 4; ++i){
      const int d = dd + i;
      const float zz = zr[(size_t)d*L_];
      const float sz = zz * frcp(1.f + ex2(-zz*LOG2E));
      const float v = ((float*)&tv)[i];
      gr[(size_t)d*L_] = fmaf((v - mu)*rstd, lnw[d], lnb[d]) * sz;
    }
  }
}

// ---------------- k5b: out_proj + residual (unchanged) ----------------
__global__ __launch_bounds__(256,2) void k5b_outproj(const float* __restrict__ x,
                                                     float* __restrict__ out){
  const int b = blockIdx.x >> 5;
  const int wv = threadIdx.x >> 6, lane = threadIdx.x & 63;
  const int pch = wv & 1, ch = wv >> 1;
  const int p = ((blockIdx.x & 31) << 7) + (pch << 6) + lane;
  const int c0 = ch * 48;
  float acc[48];
#pragma unroll
  for (int i = 0; i < 48; ++i) acc[i] = 0.f;
  const float* gb = d_g + (size_t)b*D_*L_ + p;
#pragma unroll 4
  for (int d = 0; d < D_; ++d){
    float gv = gb[(size_t)d*L_];
    const float* wr = d_w2T + d*C_ + c0;
#pragma unroll
    for (int i = 0; i < 48; ++i) acc[i] = fmaf(wr[i], gv, acc[i]);
  }
  const float* xb = x + (size_t)b*C_*L_ + p;
  float* ob = out + (size_t)b*C_*L_ + p;
#pragma unroll
  for (int i = 0; i < 48; ++i){
    int c = c0 + i;
    ob[(size_t)c*L_] = xb[(size_t)c*L_] + acc[i];
  }
}

extern "C" void kernel_launch(void* const* d_in, const int* in_sizes, int n_in,
                              void* d_out, int out_size, void* d_ws, size_t ws_size,
                              hipStream_t stream){
  (void)in_sizes; (void)n_in; (void)d_ws; (void)ws_size; (void)out_size;
  const float* x    = (const float*)d_in[0];
  const float* bng  = (const float*)d_in[1];
  const float* bnb  = (const float*)d_in[2];
  const float* bnm  = (const float*)d_in[3];
  const float* bnv  = (const float*)d_in[4];
  const float* ipw  = (const float*)d_in[5];
  const float* cw   = (const float*)d_in[6];
  const float* cb   = (const float*)d_in[7];
  const float* xpw  = (const float*)d_in[8];
  const float* dtw  = (const float*)d_in[9];
  const float* dtb  = (const float*)d_in[10];
  const float* alog = (const float*)d_in[11];
  const float* dsk  = (const float*)d_in[12];
  const float* lnw  = (const float*)d_in[13];
  const float* lnb  = (const float*)d_in[14];
  const float* opw  = (const float*)d_in[15];
  float* out = (float*)d_out;

  hipLaunchKernelGGL(k0_prep,     dim3(1),            dim3(256), 0, stream, xpw, opw, dsk);
  hipLaunchKernelGGL(k1_inproj,   dim3(512, 2, 4),    dim3(64),  0, stream, x, bng, bnb, bnm, bnv, ipw);
  hipLaunchKernelGGL(k2_conv,     dim3(D_, B_),       dim3(256), 0, stream, cw, cb);
  hipLaunchKernelGGL(k3_xproj,    dim3(16, 4, 8),     dim3(256), 0, stream, dtw, dtb);
  hipLaunchKernelGGL(k4a_local,   dim3(3, SSEG, 32),  dim3(64),  0, stream, alog);
  hipLaunchKernelGGL(k4c_combine, dim3(384),          dim3(256), 0, stream);
  hipLaunchKernelGGL(k4_scan,     dim3(3, SSEG, 32),  dim3(64),  0, stream, alog);
  hipLaunchKernelGGL(k5a_merge,   dim3(512),          dim3(64),  0, stream, lnw, lnb);
  hipLaunchKernelGGL(k5b_outproj, dim3(256),          dim3(256), 0, stream, x, out);
}